// Round 14
// baseline (1472.555 us; speedup 1.0000x reference)
//
#include <hip/hip_runtime.h>
#include <hip/hip_bf16.h>

#define D_DIM 1024
#define NTOK 267735
#define NEXT_ 267737   // + 2 cluster columns
#define HEADN 20000

typedef __attribute__((ext_vector_type(8))) short bf16x8;
typedef __attribute__((ext_vector_type(4))) float f32x4;
typedef __attribute__((ext_vector_type(4))) unsigned uint4v;

__device__ __forceinline__ int seg_of(int c){
  if (c < HEADN)  return 0;
  if (c < 20008)  return 1;
  if (c < 20016)  return 2;
  if (c < 200000) return 3;
  if (c < NTOK)   return 4;
  return 0; // cluster columns belong to head softmax
}

__device__ __forceinline__ unsigned pack2(float x, float y){
  __hip_bfloat16 a = __float2bfloat16(x);
  __hip_bfloat16 b = __float2bfloat16(y);
  unsigned short ua = *reinterpret_cast<unsigned short*>(&a);
  unsigned short ub = *reinterpret_cast<unsigned short*>(&b);
  return (unsigned)ua | ((unsigned)ub << 16);
}

#define BM 256
#define BN 128
#define BK 32
#define NTHREADS 512
#define KSTEPS (D_DIM/BK)   // 32
#define NCOLT 2092          // ceil(NEXT_/128)
#define NBLK 8384           // 8 XCD * 1048 (16 dead pad blocks)

#define APRIME_OFF 32768                      // byte offset of A' in ws
#define APRIME_BYTES (1024*1024*2)            // 2 MB bf16 fragment-ordered hidden

// direct global->LDS (16B/lane). Dest is wave-uniform base + lane*16 (m104);
// source address is per-lane.
__device__ __forceinline__ void stage16(const float* g, unsigned short* l){
  __builtin_amdgcn_global_load_lds(
      (const __attribute__((address_space(1))) void*)g,
      (__attribute__((address_space(3))) void*)l, 16, 0, 0);
}

// packed fp32x2 -> bf16x2 (single VALU op). Low half = x.
#define CVTPK(d, x, y) asm("v_cvt_pk_bf16_f32 %0, %1, %2" : "=v"(d) : "v"(x), "v"(y))

// Convert hidden (1024x1024 f32) -> A' bf16 in MFMA-fragment order:
// A'[rb(64)][kc(128)][r16(16)][e(8)]; wave frag load = 1024 contiguous bytes.
__global__ void prep_convert(const float* __restrict__ hidden,
                             unsigned short* __restrict__ Ap)
{
  int t = blockIdx.x * blockDim.x + threadIdx.x;   // 0..131071
  int r16 = t & 15, kc = (t >> 4) & 127, rb = t >> 11;
  const float4* src = reinterpret_cast<const float4*>(hidden + ((size_t)(rb*16 + r16) * D_DIM + kc*8));
  float4 x = src[0], y = src[1];
  uint4 o;
  o.x = pack2(x.x, x.y); o.y = pack2(x.z, x.w);
  o.z = pack2(y.x, y.y); o.w = pack2(y.z, y.w);
  reinterpret_cast<uint4*>(Ap)[t] = o;             // dst = t*16B: fully coalesced
}

// Per-(row, segment) sum of exp(logit + bias) into accg[row*8 + seg].
// R14 = R13 + T3/T4: TRIPLE-buffered B stage, counted s_waitcnt vmcnt(2)
// (kt+1's DMAs done; kt+2's stay in flight a full extra step -> HBM latency
// covered) + raw s_barrier (no vmcnt(0) drain). Issue order pinned with
// sched_barrier(0) so the vmcnt count is exact. B LDS [h][row][16f] with
// source-side chunk XOR; consumer cvt via v_cvt_pk. A direct-from-global in
// fragment order (R8).
__global__ __launch_bounds__(NTHREADS, 1) void gemm_lse_adir(
    const unsigned short* __restrict__ Ap, const float* __restrict__ W,
    const float* __restrict__ bias,   const float* __restrict__ cw,
    const float* __restrict__ cb,     float* __restrict__ accg)
{
  const int b = blockIdx.x;
  const int k8 = b & 7;                // XCD slot
  const int sq_ = b >> 3;              // sequence within XCD
  const int xb = sq_ & 3;              // row-block 0..3 (sharers adjacent)
  const int yb = (sq_ >> 2) * 8 + k8;  // col-strip
  if (yb >= NCOLT) return;             // pad blocks

  // B triple buffer: fp32 tile as [h][row][16 floats] = 16 KB each.
  __shared__ unsigned short lsB0[BN * 64];
  __shared__ unsigned short lsB1[BN * 64];
  __shared__ unsigned short lsB2[BN * 64];

  const int tid = threadIdx.x;
  const int rowBase = xb * BM;
  const int colBase = yb * BN;

  const int lane = tid & 63;
  const int wv = tid >> 6;
  const int wm = wv >> 1;   // 0..3 : 64-row slab
  const int wn = wv & 1;    // 0..1 : 64-col slab
  const int q  = lane >> 4; // k-chunk
  const int r16 = lane & 15;

  // ---- B stage source pointer: wave wv covers rows wv*16..+16; lane ->
  // (row_local = lane>>2, dest chunk = lane&3); source chunk XOR'd (involution
  // with the read).
  const float* sp;
  {
    int srow = wv*16 + (lane >> 2);
    int c    = (lane & 3) ^ ((srow >> 1) & 3);
    int col  = colBase + srow;
    const float* base = (col < NTOK)  ? (W  + (size_t)col * D_DIM)
                      : (col < NEXT_) ? (cw + (size_t)(col - NTOK) * D_DIM) : W;
    sp = base + c*4;
  }
  const int dstH0 = wv*512;            // h=0 region (ushort units)
  const int dstH1 = 4096 + wv*512;     // h=1 region

#define STAGE(Lbuf, kn) do{ \
    stage16(sp + (kn)*BK,      &Lbuf[dstH0]); \
    stage16(sp + (kn)*BK + 16, &Lbuf[dstH1]); }while(0)

  // ---- consumer B-fragment offsets (ushort units) ----
  int loO[4], hiO[4];
#pragma unroll
  for (int j=0;j<4;++j){
    int row = wn*64 + j*16 + r16;
    int swz = (row >> 1) & 3;
    int h   = q >> 1;
    loO[j] = h*4096 + row*32 + (((2*q  ) & 3) ^ swz)*8;
    hiO[j] = h*4096 + row*32 + (((2*q+1) & 3) ^ swz)*8;
  }

  // A' fragment pointers (ushort units): frag i at a_i + kt*512
  const unsigned short* a0 = Ap + (size_t)(xb*16 + wm*4 + 0)*16384 + q*128 + r16*8;
  const unsigned short* a1 = Ap + (size_t)(xb*16 + wm*4 + 1)*16384 + q*128 + r16*8;
  const unsigned short* a2 = Ap + (size_t)(xb*16 + wm*4 + 2)*16384 + q*128 + r16*8;
  const unsigned short* a3 = Ap + (size_t)(xb*16 + wm*4 + 3)*16384 + q*128 + r16*8;

  f32x4 acc[4][4];
#pragma unroll
  for (int i=0;i<4;++i)
#pragma unroll
    for (int j=0;j<4;++j) acc[i][j] = (f32x4){0.f,0.f,0.f,0.f};

#define BFRAG(Lr, j, out) { \
    float4 lo = *reinterpret_cast<const float4*>(&Lr[loO[j]]); \
    float4 hi = *reinterpret_cast<const float4*>(&Lr[hiO[j]]); \
    unsigned u0,u1,u2,u3; \
    CVTPK(u0, lo.x, lo.y); CVTPK(u1, lo.z, lo.w); \
    CVTPK(u2, hi.x, hi.y); CVTPK(u3, hi.z, hi.w); \
    uint4v uu; uu.x=u0; uu.y=u1; uu.z=u2; uu.w=u3; \
    out = __builtin_bit_cast(bf16x8, uu); }

  // ---- prologue: stage B(0)->buf0, B(1)->buf1; wait only B(0) ----
  STAGE(lsB0, 0);
  STAGE(lsB1, 1);
  __builtin_amdgcn_sched_barrier(0);
  asm volatile("s_waitcnt vmcnt(2)" ::: "memory");   // B(0) done; B(1) in flight
  __builtin_amdgcn_s_barrier();

  for (int kt = 0; kt < KSTEPS; ++kt){
    const int m3 = kt % 3;
    unsigned short* Lr = (m3==0) ? lsB0 : (m3==1) ? lsB1 : lsB2;
    const int w3 = (kt+2) % 3;
    unsigned short* Lw = (w3==0) ? lsB0 : (w3==1) ? lsB1 : lsB2;

    // A frags first (oldest VMEM of this step; consumed by MFMA's own wait)
    bf16x8 af0 = *reinterpret_cast<const bf16x8*>(a0 + kt*512);
    bf16x8 af1 = *reinterpret_cast<const bf16x8*>(a1 + kt*512);
    bf16x8 af2 = *reinterpret_cast<const bf16x8*>(a2 + kt*512);
    bf16x8 af3 = *reinterpret_cast<const bf16x8*>(a3 + kt*512);
    __builtin_amdgcn_sched_barrier(0);   // pin: A loads issue before stages

    if (kt + 2 < KSTEPS) STAGE(Lw, kt+2);   // newest VMEM: in flight 2 steps

    bf16x8 b0, b1, b2, b3;
    BFRAG(Lr, 0, b0); BFRAG(Lr, 1, b1); BFRAG(Lr, 2, b2); BFRAG(Lr, 3, b3);

    acc[0][0] = __builtin_amdgcn_mfma_f32_16x16x32_bf16(af0, b0, acc[0][0], 0,0,0);
    acc[0][1] = __builtin_amdgcn_mfma_f32_16x16x32_bf16(af0, b1, acc[0][1], 0,0,0);
    acc[0][2] = __builtin_amdgcn_mfma_f32_16x16x32_bf16(af0, b2, acc[0][2], 0,0,0);
    acc[0][3] = __builtin_amdgcn_mfma_f32_16x16x32_bf16(af0, b3, acc[0][3], 0,0,0);
    acc[1][0] = __builtin_amdgcn_mfma_f32_16x16x32_bf16(af1, b0, acc[1][0], 0,0,0);
    acc[1][1] = __builtin_amdgcn_mfma_f32_16x16x32_bf16(af1, b1, acc[1][1], 0,0,0);
    acc[1][2] = __builtin_amdgcn_mfma_f32_16x16x32_bf16(af1, b2, acc[1][2], 0,0,0);
    acc[1][3] = __builtin_amdgcn_mfma_f32_16x16x32_bf16(af1, b3, acc[1][3], 0,0,0);
    acc[2][0] = __builtin_amdgcn_mfma_f32_16x16x32_bf16(af2, b0, acc[2][0], 0,0,0);
    acc[2][1] = __builtin_amdgcn_mfma_f32_16x16x32_bf16(af2, b1, acc[2][1], 0,0,0);
    acc[2][2] = __builtin_amdgcn_mfma_f32_16x16x32_bf16(af2, b2, acc[2][2], 0,0,0);
    acc[2][3] = __builtin_amdgcn_mfma_f32_16x16x32_bf16(af2, b3, acc[2][3], 0,0,0);
    acc[3][0] = __builtin_amdgcn_mfma_f32_16x16x32_bf16(af3, b0, acc[3][0], 0,0,0);
    acc[3][1] = __builtin_amdgcn_mfma_f32_16x16x32_bf16(af3, b1, acc[3][1], 0,0,0);
    acc[3][2] = __builtin_amdgcn_mfma_f32_16x16x32_bf16(af3, b2, acc[3][2], 0,0,0);
    acc[3][3] = __builtin_amdgcn_mfma_f32_16x16x32_bf16(af3, b3, acc[3][3], 0,0,0);

    if (kt < KSTEPS - 1){
      __builtin_amdgcn_sched_barrier(0);   // nothing crosses the fence
      if (kt + 2 < KSTEPS)
        asm volatile("s_waitcnt vmcnt(2)" ::: "memory");  // stage(kt+1) done
      else
        asm volatile("s_waitcnt vmcnt(0)" ::: "memory");  // tail: drain last
      __builtin_amdgcn_s_barrier();        // raw: no vmcnt drain
    }
  }

  // ---- fused epilogue: exp + segmented reduce + atomic ----
  int sq[4]; float bq[4];
#pragma unroll
  for (int f=0; f<4; ++f){
    int c = colBase + wn*64 + f*16 + r16;
    if (c < NTOK)       { sq[f] = seg_of(c); bq[f] = bias[c]; }
    else if (c < NEXT_) { sq[f] = 0;         bq[f] = cb[c - NTOK]; }
    else                { sq[f] = -1;        bq[f] = 0.f; }
  }
  int sfirst = seg_of(colBase);
  int clast  = colBase + BN - 1; if (clast > NEXT_-1) clast = NEXT_-1;
  int slast  = seg_of(clast);
  int smin = sfirst, smax = slast;
  if (slast < sfirst){ smin = 0; smax = 4; }   // wrap tile at N_TOKEN boundary

#pragma unroll
  for (int i=0;i<4;++i){
#pragma unroll
    for (int r=0;r<4;++r){
      float e[4];
#pragma unroll
      for (int f=0;f<4;++f) e[f] = __expf(acc[i][f][r] + bq[f]);
      int rowg = rowBase + wm*64 + i*16 + (lane>>4)*4 + r;   // C/D: row=(l>>4)*4+reg
      for (int s2 = smin; s2 <= smax; ++s2){
        float p = 0.f;
#pragma unroll
        for (int f=0;f<4;++f) p += (sq[f]==s2) ? e[f] : 0.f;
#pragma unroll
        for (int off=1; off<16; off<<=1) p += __shfl_xor(p, off, 16);
        if ((lane & 15) == 0 && p != 0.f) atomicAdd(&accg[rowg*8 + s2], p);
      }
    }
  }
}

// One wave per row: target logit + routing logit + final nll.
__global__ __launch_bounds__(256) void finalize_kernel(
    const float* __restrict__ hidden, const int* __restrict__ target,
    const float* __restrict__ W,      const float* __restrict__ bias,
    const float* __restrict__ cw,     const float* __restrict__ cb,
    const float* __restrict__ accg,   float* __restrict__ out)
{
  const int row  = blockIdx.x * 4 + (threadIdx.x >> 6);
  const int lane = threadIdx.x & 63;
  const int t = target[row];

  const float4* h4 = reinterpret_cast<const float4*>(hidden + (size_t)row * D_DIM);
  const float4* w1 = reinterpret_cast<const float4*>(W + (size_t)t * D_DIM);
  int s = 0; const float* jraw = W; float jb = 0.f;
  if (t >= HEADN){
    if      (t < 20008)  { s=1; jraw = W;          jb = bias[0]; }  // j = 0
    else if (t < 20016)  { s=2; jraw = W + D_DIM;  jb = bias[1]; }  // j = 1
    else if (t < 200000) { s=3; jraw = cw + D_DIM; jb = cb[1];   }  // j = 20001 -> cluster 1
    else                 { s=4; jraw = cw;         jb = cb[0];   }  // j = 20000 -> cluster 0
  }
  const float4* w2 = reinterpret_cast<const float4*>(jraw);

  float p1 = 0.f, p2 = 0.f;
#pragma unroll
  for (int j=0;j<4;++j){
    float4 hv = h4[lane + 64*j];
    float4 av = w1[lane + 64*j];
    float4 bv = w2[lane + 64*j];
    p1 += hv.x*av.x + hv.y*av.y + hv.z*av.z + hv.w*av.w;
    p2 += hv.x*bv.x + hv.y*bv.y + hv.z*bv.z + hv.w*bv.w;
  }
#pragma unroll
  for (int off=32; off; off>>=1){
    p1 += __shfl_xor(p1, off, 64);
    p2 += __shfl_xor(p2, off, 64);
  }

  if (lane == 0){
    float lseH = __logf(accg[row*8 + 0]);
    float nll;
    if (t < HEADN){
      nll = -(p1 + bias[t] - lseH);
    } else {
      float lseS = __logf(accg[row*8 + s]);
      nll = -((p2 + jb - lseH) + (p1 + bias[t] - lseS));
    }
    out[row] = nll;
  }
}

extern "C" void kernel_launch(void* const* d_in, const int* in_sizes, int n_in,
                              void* d_out, int out_size, void* d_ws, size_t ws_size,
                              hipStream_t stream)
{
  const float* hidden = (const float*)d_in[0];
  const int*   target = (const int*)  d_in[1];
  const float* W      = (const float*)d_in[2];
  const float* bias   = (const float*)d_in[3];
  const float* cw     = (const float*)d_in[4];
  const float* cb     = (const float*)d_in[5];
  float* out  = (float*)d_out;
  float* accg = (float*)d_ws;          // [1024][8] fp32 sum-of-exp accumulators
  unsigned short* Ap = (unsigned short*)((char*)d_ws + APRIME_OFF);

  hipMemsetAsync(accg, 0, 1024*8*sizeof(float), stream);

  prep_convert<<<512, 256, 0, stream>>>(hidden, Ap);
  gemm_lse_adir<<<NBLK, NTHREADS, 0, stream>>>(Ap, W, bias, cw, cb, accg);
  finalize_kernel<<<256, 256, 0, stream>>>(hidden, target, W, bias, cw, cb, accg, out);
}

// Round 15
// 1045.444 us; speedup vs baseline: 1.4085x; 1.4085x over previous
//
#include <hip/hip_runtime.h>
#include <hip/hip_bf16.h>

#define D_DIM 1024
#define NTOK 267735
#define NEXT_ 267737   // + 2 cluster columns
#define HEADN 20000

typedef __attribute__((ext_vector_type(8))) short bf16x8;
typedef __attribute__((ext_vector_type(4))) float f32x4;
typedef __attribute__((ext_vector_type(4))) unsigned uint4v;

__device__ __forceinline__ int seg_of(int c){
  if (c < HEADN)  return 0;
  if (c < 20008)  return 1;
  if (c < 20016)  return 2;
  if (c < 200000) return 3;
  if (c < NTOK)   return 4;
  return 0; // cluster columns belong to head softmax
}

__device__ __forceinline__ unsigned pack2(float x, float y){
  __hip_bfloat16 a = __float2bfloat16(x);
  __hip_bfloat16 b = __float2bfloat16(y);
  unsigned short ua = *reinterpret_cast<unsigned short*>(&a);
  unsigned short ub = *reinterpret_cast<unsigned short*>(&b);
  return (unsigned)ua | ((unsigned)ub << 16);
}

#define BM 128
#define BN 128
#define BK 32
#define NTHREADS 256        // 4 waves: 2 row-slabs x 2 col-slabs (64x64 wave tile)
#define KSTEPS (D_DIM/BK)   // 32
#define NCOLT 2092          // ceil(NEXT_/128)
#define NBLK 16768          // 8 XCD * 2096 (32 dead pad blocks)

#define APRIME_OFF 32768                      // byte offset of A' in ws
#define APRIME_BYTES (1024*1024*2)            // 2 MB bf16 fragment-ordered hidden

// direct global->LDS (16B/lane). Dest is wave-uniform base + lane*16 (m104);
// source address is per-lane.
__device__ __forceinline__ void stage16(const float* g, unsigned short* l){
  __builtin_amdgcn_global_load_lds(
      (const __attribute__((address_space(1))) void*)g,
      (__attribute__((address_space(3))) void*)l, 16, 0, 0);
}

// packed fp32x2 -> bf16x2 (single VALU op). Low half = x.
#define CVTPK(d, x, y) asm("v_cvt_pk_bf16_f32 %0, %1, %2" : "=v"(d) : "v"(x), "v"(y))

// Convert hidden (1024x1024 f32) -> A' bf16 in MFMA-fragment order:
// A'[rb(64)][kc(128)][r16(16)][e(8)]; wave frag load = 1024 contiguous bytes.
__global__ void prep_convert(const float* __restrict__ hidden,
                             unsigned short* __restrict__ Ap)
{
  int t = blockIdx.x * blockDim.x + threadIdx.x;   // 0..131071
  int r16 = t & 15, kc = (t >> 4) & 127, rb = t >> 11;
  const float4* src = reinterpret_cast<const float4*>(hidden + ((size_t)(rb*16 + r16) * D_DIM + kc*8));
  float4 x = src[0], y = src[1];
  uint4 o;
  o.x = pack2(x.x, x.y); o.y = pack2(x.z, x.w);
  o.z = pack2(y.x, y.y); o.w = pack2(y.z, y.w);
  reinterpret_cast<uint4*>(Ap)[t] = o;             // dst = t*16B: fully coalesced
}

// Per-(row, segment) sum of exp(logit + bias) into accg[row*8 + seg].
// R15 = R13 datapath at 128x128 blocks (256 threads, 4 waves): same B tile
// (BN=128, fp32 DMA to [h][row][16f] LDS, source-side chunk XOR, consumer
// cvt_pk), same A'-direct, same 1 __syncthreads/step — but FOUR independent
// barrier-groups per CU (124 regs/wave -> 4 waves/SIMD; LDS 32KB*4=128KB).
// When one group stalls at its barrier (DMA drain), three others fill the CU.
// XCD remap: the 8 row-blocks sharing one 128-col W strip -> same XCD.
__global__ __launch_bounds__(NTHREADS, 1) void gemm_lse_adir(
    const unsigned short* __restrict__ Ap, const float* __restrict__ W,
    const float* __restrict__ bias,   const float* __restrict__ cw,
    const float* __restrict__ cb,     float* __restrict__ accg)
{
  const int b = blockIdx.x;
  const int k8 = b & 7;                // XCD slot
  const int sq_ = b >> 3;              // sequence within XCD (0..2095)
  const int xb = sq_ & 7;              // row-block 0..7 (sharers adjacent)
  const int yb = (sq_ >> 3) * 8 + k8;  // col-strip
  if (yb >= NCOLT) return;             // pad blocks

  // B double buffer: fp32 tile as [h][row][16 floats] = 16 KB each.
  __shared__ unsigned short lsB0[BN * 64];
  __shared__ unsigned short lsB1[BN * 64];

  const int tid = threadIdx.x;
  const int rowBase = xb * BM;
  const int colBase = yb * BN;

  const int lane = tid & 63;
  const int wv = tid >> 6;  // 0..3
  const int wm = wv >> 1;   // 0..1 : 64-row slab
  const int wn = wv & 1;    // 0..1 : 64-col slab
  const int q  = lane >> 4; // k-chunk
  const int r16 = lane & 15;

  // ---- B stage source pointers: wave wv covers rows wv*16..+16 and +64..;
  // lane -> (row_local = lane>>2, dest chunk = lane&3); source chunk XOR'd
  // (involution with the read). (srow+64)>>1 & 3 == srow>>1 & 3, so the
  // same chunk XOR applies to both halves.
  const float* sp;  const float* sp2;
  {
    int srow = wv*16 + (lane >> 2);
    int c    = (lane & 3) ^ ((srow >> 1) & 3);
    int col  = colBase + srow;
    const float* base = (col < NTOK)  ? (W  + (size_t)col * D_DIM)
                      : (col < NEXT_) ? (cw + (size_t)(col - NTOK) * D_DIM) : W;
    sp = base + c*4;
    int col2 = col + 64;
    const float* base2 = (col2 < NTOK)  ? (W  + (size_t)col2 * D_DIM)
                       : (col2 < NEXT_) ? (cw + (size_t)(col2 - NTOK) * D_DIM) : W;
    sp2 = base2 + c*4;
  }
  const int dstH0 = wv*512;            // h=0, rows wv*16.. (ushort units)
  const int dstH1 = 4096 + wv*512;     // h=1, rows wv*16..
  // rows +64: offset 64*32 = 2048 ushorts

#define STAGE(Lbuf, kn) do{ \
    stage16(sp  + (kn)*BK,      &Lbuf[dstH0]); \
    stage16(sp  + (kn)*BK + 16, &Lbuf[dstH1]); \
    stage16(sp2 + (kn)*BK,      &Lbuf[dstH0 + 2048]); \
    stage16(sp2 + (kn)*BK + 16, &Lbuf[dstH1 + 2048]); }while(0)

  // ---- consumer B-fragment offsets (ushort units) ----
  int loO[4], hiO[4];
#pragma unroll
  for (int j=0;j<4;++j){
    int row = wn*64 + j*16 + r16;
    int swz = (row >> 1) & 3;
    int h   = q >> 1;
    loO[j] = h*4096 + row*32 + (((2*q  ) & 3) ^ swz)*8;
    hiO[j] = h*4096 + row*32 + (((2*q+1) & 3) ^ swz)*8;
  }

  // A' fragment pointers (ushort units): frag i at a_i + kt*512
  const unsigned short* a0 = Ap + (size_t)(xb*8 + wm*4 + 0)*16384 + q*128 + r16*8;
  const unsigned short* a1 = Ap + (size_t)(xb*8 + wm*4 + 1)*16384 + q*128 + r16*8;
  const unsigned short* a2 = Ap + (size_t)(xb*8 + wm*4 + 2)*16384 + q*128 + r16*8;
  const unsigned short* a3 = Ap + (size_t)(xb*8 + wm*4 + 3)*16384 + q*128 + r16*8;

  f32x4 acc[4][4];
#pragma unroll
  for (int i=0;i<4;++i)
#pragma unroll
    for (int j=0;j<4;++j) acc[i][j] = (f32x4){0.f,0.f,0.f,0.f};

#define BFRAG(Lr, j, out) { \
    float4 lo = *reinterpret_cast<const float4*>(&Lr[loO[j]]); \
    float4 hi = *reinterpret_cast<const float4*>(&Lr[hiO[j]]); \
    unsigned u0,u1,u2,u3; \
    CVTPK(u0, lo.x, lo.y); CVTPK(u1, lo.z, lo.w); \
    CVTPK(u2, hi.x, hi.y); CVTPK(u3, hi.z, hi.w); \
    uint4v uu; uu.x=u0; uu.y=u1; uu.z=u2; uu.w=u3; \
    out = __builtin_bit_cast(bf16x8, uu); }

  // ---- prologue: stage B(0) into buf0 ----
  STAGE(lsB0, 0);
  __syncthreads();   // vmcnt(0)+lgkmcnt(0) drain publishes the stage

  for (int kt = 0; kt < KSTEPS; ++kt){
    unsigned short* Lr = (kt & 1) ? lsB1 : lsB0;
    unsigned short* Lw = (kt & 1) ? lsB0 : lsB1;

    // A frags first (so MFMA's counted vmcnt wait leaves the stage in flight)
    bf16x8 af0 = *reinterpret_cast<const bf16x8*>(a0 + kt*512);
    bf16x8 af1 = *reinterpret_cast<const bf16x8*>(a1 + kt*512);
    bf16x8 af2 = *reinterpret_cast<const bf16x8*>(a2 + kt*512);
    bf16x8 af3 = *reinterpret_cast<const bf16x8*>(a3 + kt*512);

    if (kt + 1 < KSTEPS) STAGE(Lw, kt+1);   // flies under this step's MFMAs

    bf16x8 b0, b1, b2, b3;
    BFRAG(Lr, 0, b0); BFRAG(Lr, 1, b1); BFRAG(Lr, 2, b2); BFRAG(Lr, 3, b3);

    acc[0][0] = __builtin_amdgcn_mfma_f32_16x16x32_bf16(af0, b0, acc[0][0], 0,0,0);
    acc[0][1] = __builtin_amdgcn_mfma_f32_16x16x32_bf16(af0, b1, acc[0][1], 0,0,0);
    acc[0][2] = __builtin_amdgcn_mfma_f32_16x16x32_bf16(af0, b2, acc[0][2], 0,0,0);
    acc[0][3] = __builtin_amdgcn_mfma_f32_16x16x32_bf16(af0, b3, acc[0][3], 0,0,0);
    acc[1][0] = __builtin_amdgcn_mfma_f32_16x16x32_bf16(af1, b0, acc[1][0], 0,0,0);
    acc[1][1] = __builtin_amdgcn_mfma_f32_16x16x32_bf16(af1, b1, acc[1][1], 0,0,0);
    acc[1][2] = __builtin_amdgcn_mfma_f32_16x16x32_bf16(af1, b2, acc[1][2], 0,0,0);
    acc[1][3] = __builtin_amdgcn_mfma_f32_16x16x32_bf16(af1, b3, acc[1][3], 0,0,0);
    acc[2][0] = __builtin_amdgcn_mfma_f32_16x16x32_bf16(af2, b0, acc[2][0], 0,0,0);
    acc[2][1] = __builtin_amdgcn_mfma_f32_16x16x32_bf16(af2, b1, acc[2][1], 0,0,0);
    acc[2][2] = __builtin_amdgcn_mfma_f32_16x16x32_bf16(af2, b2, acc[2][2], 0,0,0);
    acc[2][3] = __builtin_amdgcn_mfma_f32_16x16x32_bf16(af2, b3, acc[2][3], 0,0,0);
    acc[3][0] = __builtin_amdgcn_mfma_f32_16x16x32_bf16(af3, b0, acc[3][0], 0,0,0);
    acc[3][1] = __builtin_amdgcn_mfma_f32_16x16x32_bf16(af3, b1, acc[3][1], 0,0,0);
    acc[3][2] = __builtin_amdgcn_mfma_f32_16x16x32_bf16(af3, b2, acc[3][2], 0,0,0);
    acc[3][3] = __builtin_amdgcn_mfma_f32_16x16x32_bf16(af3, b3, acc[3][3], 0,0,0);

    __syncthreads();   // drains vmcnt(0): stage(kt+1) complete & visible
  }

  // ---- fused epilogue: exp + segmented reduce + atomic ----
  int sq[4]; float bq[4];
#pragma unroll
  for (int f=0; f<4; ++f){
    int c = colBase + wn*64 + f*16 + r16;
    if (c < NTOK)       { sq[f] = seg_of(c); bq[f] = bias[c]; }
    else if (c < NEXT_) { sq[f] = 0;         bq[f] = cb[c - NTOK]; }
    else                { sq[f] = -1;        bq[f] = 0.f; }
  }
  int sfirst = seg_of(colBase);
  int clast  = colBase + BN - 1; if (clast > NEXT_-1) clast = NEXT_-1;
  int slast  = seg_of(clast);
  int smin = sfirst, smax = slast;
  if (slast < sfirst){ smin = 0; smax = 4; }   // wrap tile at N_TOKEN boundary

#pragma unroll
  for (int i=0;i<4;++i){
#pragma unroll
    for (int r=0;r<4;++r){
      float e[4];
#pragma unroll
      for (int f=0;f<4;++f) e[f] = __expf(acc[i][f][r] + bq[f]);
      int rowg = rowBase + wm*64 + i*16 + (lane>>4)*4 + r;   // C/D: row=(l>>4)*4+reg
      for (int s2 = smin; s2 <= smax; ++s2){
        float p = 0.f;
#pragma unroll
        for (int f=0;f<4;++f) p += (sq[f]==s2) ? e[f] : 0.f;
#pragma unroll
        for (int off=1; off<16; off<<=1) p += __shfl_xor(p, off, 16);
        if ((lane & 15) == 0 && p != 0.f) atomicAdd(&accg[rowg*8 + s2], p);
      }
    }
  }
}

// One wave per row: target logit + routing logit + final nll.
__global__ __launch_bounds__(256) void finalize_kernel(
    const float* __restrict__ hidden, const int* __restrict__ target,
    const float* __restrict__ W,      const float* __restrict__ bias,
    const float* __restrict__ cw,     const float* __restrict__ cb,
    const float* __restrict__ accg,   float* __restrict__ out)
{
  const int row  = blockIdx.x * 4 + (threadIdx.x >> 6);
  const int lane = threadIdx.x & 63;
  const int t = target[row];

  const float4* h4 = reinterpret_cast<const float4*>(hidden + (size_t)row * D_DIM);
  const float4* w1 = reinterpret_cast<const float4*>(W + (size_t)t * D_DIM);
  int s = 0; const float* jraw = W; float jb = 0.f;
  if (t >= HEADN){
    if      (t < 20008)  { s=1; jraw = W;          jb = bias[0]; }  // j = 0
    else if (t < 20016)  { s=2; jraw = W + D_DIM;  jb = bias[1]; }  // j = 1
    else if (t < 200000) { s=3; jraw = cw + D_DIM; jb = cb[1];   }  // j = 20001 -> cluster 1
    else                 { s=4; jraw = cw;         jb = cb[0];   }  // j = 20000 -> cluster 0
  }
  const float4* w2 = reinterpret_cast<const float4*>(jraw);

  float p1 = 0.f, p2 = 0.f;
#pragma unroll
  for (int j=0;j<4;++j){
    float4 hv = h4[lane + 64*j];
    float4 av = w1[lane + 64*j];
    float4 bv = w2[lane + 64*j];
    p1 += hv.x*av.x + hv.y*av.y + hv.z*av.z + hv.w*av.w;
    p2 += hv.x*bv.x + hv.y*bv.y + hv.z*bv.z + hv.w*bv.w;
  }
#pragma unroll
  for (int off=32; off; off>>=1){
    p1 += __shfl_xor(p1, off, 64);
    p2 += __shfl_xor(p2, off, 64);
  }

  if (lane == 0){
    float lseH = __logf(accg[row*8 + 0]);
    float nll;
    if (t < HEADN){
      nll = -(p1 + bias[t] - lseH);
    } else {
      float lseS = __logf(accg[row*8 + s]);
      nll = -((p2 + jb - lseH) + (p1 + bias[t] - lseS));
    }
    out[row] = nll;
  }
}

extern "C" void kernel_launch(void* const* d_in, const int* in_sizes, int n_in,
                              void* d_out, int out_size, void* d_ws, size_t ws_size,
                              hipStream_t stream)
{
  const float* hidden = (const float*)d_in[0];
  const int*   target = (const int*)  d_in[1];
  const float* W      = (const float*)d_in[2];
  const float* bias   = (const float*)d_in[3];
  const float* cw     = (const float*)d_in[4];
  const float* cb     = (const float*)d_in[5];
  float* out  = (float*)d_out;
  float* accg = (float*)d_ws;          // [1024][8] fp32 sum-of-exp accumulators
  unsigned short* Ap = (unsigned short*)((char*)d_ws + APRIME_OFF);

  hipMemsetAsync(accg, 0, 1024*8*sizeof(float), stream);

  prep_convert<<<512, 256, 0, stream>>>(hidden, Ap);
  gemm_lse_adir<<<NBLK, NTHREADS, 0, stream>>>(Ap, W, bias, cw, cb, accg);
  finalize_kernel<<<256, 256, 0, stream>>>(hidden, target, W, bias, cw, cb, accg, out);
}

// Round 16
// 822.058 us; speedup vs baseline: 1.7913x; 1.2717x over previous
//
#include <hip/hip_runtime.h>
#include <hip/hip_bf16.h>

#define D_DIM 1024
#define NTOK 267735
#define NEXT_ 267737   // + 2 cluster columns
#define HEADN 20000

typedef __attribute__((ext_vector_type(8))) short bf16x8;
typedef __attribute__((ext_vector_type(4))) float f32x4;
typedef __attribute__((ext_vector_type(4))) unsigned uint4v;

__device__ __forceinline__ int seg_of(int c){
  if (c < HEADN)  return 0;
  if (c < 20008)  return 1;
  if (c < 20016)  return 2;
  if (c < 200000) return 3;
  if (c < NTOK)   return 4;
  return 0; // cluster columns belong to head softmax
}

__device__ __forceinline__ unsigned pack2(float x, float y){
  __hip_bfloat16 a = __float2bfloat16(x);
  __hip_bfloat16 b = __float2bfloat16(y);
  unsigned short ua = *reinterpret_cast<unsigned short*>(&a);
  unsigned short ub = *reinterpret_cast<unsigned short*>(&b);
  return (unsigned)ua | ((unsigned)ub << 16);
}

#define BM 256
#define BN 128
#define BK 32
#define NTHREADS 512
#define KSTEPS (D_DIM/BK)   // 32
#define NPHASE (KSTEPS/2)   // 16 (2 K-steps per phase)
#define NCOLT 2092          // ceil(NEXT_/128)
#define NBLK 8384           // 8 XCD * 1048 (16 dead pad blocks)

#define APRIME_OFF 32768                      // byte offset of A' in ws
#define APRIME_BYTES (1024*1024*2)            // 2 MB bf16 fragment-ordered hidden

// direct global->LDS (16B/lane). Dest is wave-uniform base + lane*16 (m104);
// source address is per-lane.
__device__ __forceinline__ void stage16(const float* g, unsigned short* l){
  __builtin_amdgcn_global_load_lds(
      (const __attribute__((address_space(1))) void*)g,
      (__attribute__((address_space(3))) void*)l, 16, 0, 0);
}

// packed fp32x2 -> bf16x2 (single VALU op). Low half = x.
#define CVTPK(d, x, y) asm("v_cvt_pk_bf16_f32 %0, %1, %2" : "=v"(d) : "v"(x), "v"(y))

// Convert hidden (1024x1024 f32) -> A' bf16 in MFMA-fragment order:
// A'[rb(64)][kc(128)][r16(16)][e(8)]; wave frag load = 1024 contiguous bytes.
__global__ void prep_convert(const float* __restrict__ hidden,
                             unsigned short* __restrict__ Ap)
{
  int t = blockIdx.x * blockDim.x + threadIdx.x;   // 0..131071
  int r16 = t & 15, kc = (t >> 4) & 127, rb = t >> 11;
  const float4* src = reinterpret_cast<const float4*>(hidden + ((size_t)(rb*16 + r16) * D_DIM + kc*8));
  float4 x = src[0], y = src[1];
  uint4 o;
  o.x = pack2(x.x, x.y); o.y = pack2(x.z, x.w);
  o.z = pack2(y.x, y.y); o.w = pack2(y.z, y.w);
  reinterpret_cast<uint4*>(Ap)[t] = o;             // dst = t*16B: fully coalesced
}

// Per-(row, segment) sum of exp(logit + bias) into accg[row*8 + seg].
// R16 = R13 datapath with KC=2 phase double-buffering: each LDS buffer holds
// TWO K-steps of fp32 B (32 KB); per phase we issue the next phase's 4-DMA
// stage into the other buffer, run 2 barrier-free K-steps (compiler pipelines
// across them), then ONE __syncthreads. Sync count 32 -> 16; the stage has a
// full 2-step compute phase in flight before its drain. Same 512 threads,
// same 2 blocks/CU, same ~60-reg class, same [h][row][16f] + source-XOR
// layout, same consumer cvt_pk, same A'-direct (R8), same XCD remap.
__global__ __launch_bounds__(NTHREADS, 1) void gemm_lse_adir(
    const unsigned short* __restrict__ Ap, const float* __restrict__ W,
    const float* __restrict__ bias,   const float* __restrict__ cw,
    const float* __restrict__ cb,     float* __restrict__ accg)
{
  const int b = blockIdx.x;
  const int k8 = b & 7;                // XCD slot
  const int sq_ = b >> 3;              // sequence within XCD
  const int xb = sq_ & 3;              // row-block 0..3 (sharers adjacent)
  const int yb = (sq_ >> 2) * 8 + k8;  // col-strip
  if (yb >= NCOLT) return;             // pad blocks

  // B double buffer: TWO K-steps of fp32 as [s(2)][h(2)][row(128)][16f] = 32 KB each.
  __shared__ unsigned short lsB0[2 * BN * 64];   // 32 KB
  __shared__ unsigned short lsB1[2 * BN * 64];   // 32 KB

  const int tid = threadIdx.x;
  const int rowBase = xb * BM;
  const int colBase = yb * BN;

  const int lane = tid & 63;
  const int wv = tid >> 6;
  const int wm = wv >> 1;   // 0..3 : 64-row slab
  const int wn = wv & 1;    // 0..1 : 64-col slab
  const int q  = lane >> 4; // k-chunk
  const int r16 = lane & 15;

  // ---- B stage source pointer: wave wv covers rows wv*16..+16; lane ->
  // (row_local = lane>>2, dest chunk = lane&3); source chunk XOR'd (involution
  // with the read).
  const float* sp;
  {
    int srow = wv*16 + (lane >> 2);
    int c    = (lane & 3) ^ ((srow >> 1) & 3);
    int col  = colBase + srow;
    const float* base = (col < NTOK)  ? (W  + (size_t)col * D_DIM)
                      : (col < NEXT_) ? (cw + (size_t)(col - NTOK) * D_DIM) : W;
    sp = base + c*4;
  }
  const int dstH0 = wv*512;            // h=0 region within a step (ushort units)
  const int dstH1 = 4096 + wv*512;     // h=1 region within a step

  // stage one K-step kn into sub-buffer (kn&1) of Lbuf
#define STAGE1(Lbuf, kn) do{ \
    stage16(sp + (kn)*BK,      &Lbuf[((kn)&1)*8192 + dstH0]); \
    stage16(sp + (kn)*BK + 16, &Lbuf[((kn)&1)*8192 + dstH1]); }while(0)
#define STAGE2(Lbuf, kn) do{ STAGE1(Lbuf, kn); STAGE1(Lbuf, (kn)+1); }while(0)

  // ---- consumer B-fragment offsets (ushort units, within one step) ----
  int loO[4], hiO[4];
#pragma unroll
  for (int j=0;j<4;++j){
    int row = wn*64 + j*16 + r16;
    int swz = (row >> 1) & 3;
    int h   = q >> 1;
    loO[j] = h*4096 + row*32 + (((2*q  ) & 3) ^ swz)*8;
    hiO[j] = h*4096 + row*32 + (((2*q+1) & 3) ^ swz)*8;
  }

  // A' fragment pointers (ushort units): frag i at a_i + kt*512
  const unsigned short* a0 = Ap + (size_t)(xb*16 + wm*4 + 0)*16384 + q*128 + r16*8;
  const unsigned short* a1 = Ap + (size_t)(xb*16 + wm*4 + 1)*16384 + q*128 + r16*8;
  const unsigned short* a2 = Ap + (size_t)(xb*16 + wm*4 + 2)*16384 + q*128 + r16*8;
  const unsigned short* a3 = Ap + (size_t)(xb*16 + wm*4 + 3)*16384 + q*128 + r16*8;

  f32x4 acc[4][4];
#pragma unroll
  for (int i=0;i<4;++i)
#pragma unroll
    for (int j=0;j<4;++j) acc[i][j] = (f32x4){0.f,0.f,0.f,0.f};

#define BFRAG(Lp, j, out) { \
    float4 lo = *reinterpret_cast<const float4*>(&Lp[loO[j]]); \
    float4 hi = *reinterpret_cast<const float4*>(&Lp[hiO[j]]); \
    unsigned u0,u1,u2,u3; \
    CVTPK(u0, lo.x, lo.y); CVTPK(u1, lo.z, lo.w); \
    CVTPK(u2, hi.x, hi.y); CVTPK(u3, hi.z, hi.w); \
    uint4v uu; uu.x=u0; uu.y=u1; uu.z=u2; uu.w=u3; \
    out = __builtin_bit_cast(bf16x8, uu); }

  // one K-step: A frags direct from L2 + B frags from LDS sub-buffer + 16 MFMA
#define KSTEP(Lp, kt) do{ \
    bf16x8 af0 = *reinterpret_cast<const bf16x8*>(a0 + (kt)*512); \
    bf16x8 af1 = *reinterpret_cast<const bf16x8*>(a1 + (kt)*512); \
    bf16x8 af2 = *reinterpret_cast<const bf16x8*>(a2 + (kt)*512); \
    bf16x8 af3 = *reinterpret_cast<const bf16x8*>(a3 + (kt)*512); \
    bf16x8 b0, b1, b2, b3; \
    BFRAG(Lp, 0, b0); BFRAG(Lp, 1, b1); BFRAG(Lp, 2, b2); BFRAG(Lp, 3, b3); \
    acc[0][0] = __builtin_amdgcn_mfma_f32_16x16x32_bf16(af0, b0, acc[0][0], 0,0,0); \
    acc[0][1] = __builtin_amdgcn_mfma_f32_16x16x32_bf16(af0, b1, acc[0][1], 0,0,0); \
    acc[0][2] = __builtin_amdgcn_mfma_f32_16x16x32_bf16(af0, b2, acc[0][2], 0,0,0); \
    acc[0][3] = __builtin_amdgcn_mfma_f32_16x16x32_bf16(af0, b3, acc[0][3], 0,0,0); \
    acc[1][0] = __builtin_amdgcn_mfma_f32_16x16x32_bf16(af1, b0, acc[1][0], 0,0,0); \
    acc[1][1] = __builtin_amdgcn_mfma_f32_16x16x32_bf16(af1, b1, acc[1][1], 0,0,0); \
    acc[1][2] = __builtin_amdgcn_mfma_f32_16x16x32_bf16(af1, b2, acc[1][2], 0,0,0); \
    acc[1][3] = __builtin_amdgcn_mfma_f32_16x16x32_bf16(af1, b3, acc[1][3], 0,0,0); \
    acc[2][0] = __builtin_amdgcn_mfma_f32_16x16x32_bf16(af2, b0, acc[2][0], 0,0,0); \
    acc[2][1] = __builtin_amdgcn_mfma_f32_16x16x32_bf16(af2, b1, acc[2][1], 0,0,0); \
    acc[2][2] = __builtin_amdgcn_mfma_f32_16x16x32_bf16(af2, b2, acc[2][2], 0,0,0); \
    acc[2][3] = __builtin_amdgcn_mfma_f32_16x16x32_bf16(af2, b3, acc[2][3], 0,0,0); \
    acc[3][0] = __builtin_amdgcn_mfma_f32_16x16x32_bf16(af3, b0, acc[3][0], 0,0,0); \
    acc[3][1] = __builtin_amdgcn_mfma_f32_16x16x32_bf16(af3, b1, acc[3][1], 0,0,0); \
    acc[3][2] = __builtin_amdgcn_mfma_f32_16x16x32_bf16(af3, b2, acc[3][2], 0,0,0); \
    acc[3][3] = __builtin_amdgcn_mfma_f32_16x16x32_bf16(af3, b3, acc[3][3], 0,0,0); \
  }while(0)

  // ---- prologue: stage phase 0 (steps 0,1) into buf0 ----
  STAGE2(lsB0, 0);
  __syncthreads();   // vmcnt(0)+lgkmcnt(0) drain publishes the stage

  for (int p = 0; p < NPHASE; ++p){
    unsigned short* Lr = (p & 1) ? lsB1 : lsB0;
    unsigned short* Lw = (p & 1) ? lsB0 : lsB1;
    const int k0 = 2*p;

    if (p + 1 < NPHASE) STAGE2(Lw, k0+2);   // in flight across the whole phase

    KSTEP(Lr,          k0    );            // sub-step 0 (sub-buffer 0)
    KSTEP((Lr + 8192), k0 + 1);            // sub-step 1 (sub-buffer 1)

    __syncthreads();   // drains vmcnt(0): stage(p+1) complete & visible
  }

  // ---- fused epilogue: exp + segmented reduce + atomic ----
  int sq[4]; float bq[4];
#pragma unroll
  for (int f=0; f<4; ++f){
    int c = colBase + wn*64 + f*16 + r16;
    if (c < NTOK)       { sq[f] = seg_of(c); bq[f] = bias[c]; }
    else if (c < NEXT_) { sq[f] = 0;         bq[f] = cb[c - NTOK]; }
    else                { sq[f] = -1;        bq[f] = 0.f; }
  }
  int sfirst = seg_of(colBase);
  int clast  = colBase + BN - 1; if (clast > NEXT_-1) clast = NEXT_-1;
  int slast  = seg_of(clast);
  int smin = sfirst, smax = slast;
  if (slast < sfirst){ smin = 0; smax = 4; }   // wrap tile at N_TOKEN boundary

#pragma unroll
  for (int i=0;i<4;++i){
#pragma unroll
    for (int r=0;r<4;++r){
      float e[4];
#pragma unroll
      for (int f=0;f<4;++f) e[f] = __expf(acc[i][f][r] + bq[f]);
      int rowg = rowBase + wm*64 + i*16 + (lane>>4)*4 + r;   // C/D: row=(l>>4)*4+reg
      for (int s2 = smin; s2 <= smax; ++s2){
        float p2 = 0.f;
#pragma unroll
        for (int f=0;f<4;++f) p2 += (sq[f]==s2) ? e[f] : 0.f;
#pragma unroll
        for (int off=1; off<16; off<<=1) p2 += __shfl_xor(p2, off, 16);
        if ((lane & 15) == 0 && p2 != 0.f) atomicAdd(&accg[rowg*8 + s2], p2);
      }
    }
  }
}

// One wave per row: target logit + routing logit + final nll.
__global__ __launch_bounds__(256) void finalize_kernel(
    const float* __restrict__ hidden, const int* __restrict__ target,
    const float* __restrict__ W,      const float* __restrict__ bias,
    const float* __restrict__ cw,     const float* __restrict__ cb,
    const float* __restrict__ accg,   float* __restrict__ out)
{
  const int row  = blockIdx.x * 4 + (threadIdx.x >> 6);
  const int lane = threadIdx.x & 63;
  const int t = target[row];

  const float4* h4 = reinterpret_cast<const float4*>(hidden + (size_t)row * D_DIM);
  const float4* w1 = reinterpret_cast<const float4*>(W + (size_t)t * D_DIM);
  int s = 0; const float* jraw = W; float jb = 0.f;
  if (t >= HEADN){
    if      (t < 20008)  { s=1; jraw = W;          jb = bias[0]; }  // j = 0
    else if (t < 20016)  { s=2; jraw = W + D_DIM;  jb = bias[1]; }  // j = 1
    else if (t < 200000) { s=3; jraw = cw + D_DIM; jb = cb[1];   }  // j = 20001 -> cluster 1
    else                 { s=4; jraw = cw;         jb = cb[0];   }  // j = 20000 -> cluster 0
  }
  const float4* w2 = reinterpret_cast<const float4*>(jraw);

  float p1 = 0.f, p2 = 0.f;
#pragma unroll
  for (int j=0;j<4;++j){
    float4 hv = h4[lane + 64*j];
    float4 av = w1[lane + 64*j];
    float4 bv = w2[lane + 64*j];
    p1 += hv.x*av.x + hv.y*av.y + hv.z*av.z + hv.w*av.w;
    p2 += hv.x*bv.x + hv.y*bv.y + hv.z*bv.z + hv.w*bv.w;
  }
#pragma unroll
  for (int off=32; off; off>>=1){
    p1 += __shfl_xor(p1, off, 64);
    p2 += __shfl_xor(p2, off, 64);
  }

  if (lane == 0){
    float lseH = __logf(accg[row*8 + 0]);
    float nll;
    if (t < HEADN){
      nll = -(p1 + bias[t] - lseH);
    } else {
      float lseS = __logf(accg[row*8 + s]);
      nll = -((p2 + jb - lseH) + (p1 + bias[t] - lseS));
    }
    out[row] = nll;
  }
}

extern "C" void kernel_launch(void* const* d_in, const int* in_sizes, int n_in,
                              void* d_out, int out_size, void* d_ws, size_t ws_size,
                              hipStream_t stream)
{
  const float* hidden = (const float*)d_in[0];
  const int*   target = (const int*)  d_in[1];
  const float* W      = (const float*)d_in[2];
  const float* bias   = (const float*)d_in[3];
  const float* cw     = (const float*)d_in[4];
  const float* cb     = (const float*)d_in[5];
  float* out  = (float*)d_out;
  float* accg = (float*)d_ws;          // [1024][8] fp32 sum-of-exp accumulators
  unsigned short* Ap = (unsigned short*)((char*)d_ws + APRIME_OFF);

  hipMemsetAsync(accg, 0, 1024*8*sizeof(float), stream);

  prep_convert<<<512, 256, 0, stream>>>(hidden, Ap);
  gemm_lse_adir<<<NBLK, NTHREADS, 0, stream>>>(Ap, W, bias, cw, cb, accg);
  finalize_kernel<<<256, 256, 0, stream>>>(hidden, target, W, bias, cw, cb, accg, out);
}